// Round 1
// baseline (26294.513 us; speedup 1.0000x reference)
//
#include <hip/hip_runtime.h>

#define Bv    32
#define Lv    256
#define Ev    256
#define HIDv  512
#define MEMv  128
#define HSv   64
#define NHv   4
#define OUTv  256
#define CTRLv 512
#define GATESv 2048
#define HPDv  129

#define NBLK  256
#define NTHR  512

// ws float offsets
#define G_OFF   1024                           // gates: 32*2048
#define H_OFF   (G_OFF + Bv*GATESv)            // hbuf: 2 * 32*512
#define C_OFF   (H_OFF + 2*Bv*HIDv)            // cbuf: 2 * 32*512
#define R_OFF   (C_OFF + 2*Bv*HIDv)            // rcbuf: 2 * 32*256
#define P_OFF   (R_OFF + 2*Bv*NHv*HSv)         // hp: 32*4*129

__device__ __forceinline__ float sigm(float x) { return 1.0f / (1.0f + __expf(-x)); }
__device__ __forceinline__ float tanh_(float x) {
  float ax = fabsf(x);
  float e = __expf(-2.0f * ax);
  float t = (1.0f - e) / (1.0f + e);
  return copysignf(t, x);
}
__device__ __forceinline__ float dot4(float4 a, float4 b) {
  return fmaf(a.x, b.x, fmaf(a.y, b.y, fmaf(a.z, b.z, a.w * b.w)));
}

// Two-level grid barrier: 16 groups x 16 blocks. bar[0]=gen, bar[32]=root,
// bar[64+g*32]=group counters (128B separated). Agent scope for cross-XCD.
__device__ __forceinline__ void gbar(unsigned* bar, int bk) {
  __syncthreads();
  if (threadIdx.x == 0) {
    unsigned g = __hip_atomic_load(&bar[0], __ATOMIC_ACQUIRE, __HIP_MEMORY_SCOPE_AGENT);
    __threadfence();  // release this block's prior writes to agent scope
    unsigned* gc = &bar[64 + (bk >> 4) * 32];
    if (__hip_atomic_fetch_add(gc, 1u, __ATOMIC_ACQ_REL, __HIP_MEMORY_SCOPE_AGENT) == 15u) {
      __hip_atomic_store(gc, 0u, __ATOMIC_RELAXED, __HIP_MEMORY_SCOPE_AGENT);
      if (__hip_atomic_fetch_add(&bar[32], 1u, __ATOMIC_ACQ_REL, __HIP_MEMORY_SCOPE_AGENT) == 15u) {
        __hip_atomic_store(&bar[32], 0u, __ATOMIC_RELAXED, __HIP_MEMORY_SCOPE_AGENT);
        __hip_atomic_fetch_add(&bar[0], 1u, __ATOMIC_RELEASE, __HIP_MEMORY_SCOPE_AGENT);
      }
    }
    while (__hip_atomic_load(&bar[0], __ATOMIC_RELAXED, __HIP_MEMORY_SCOPE_AGENT) == g) {
      __builtin_amdgcn_s_sleep(1);
    }
    __threadfence();  // acquire: invalidate stale L1/L2 before consuming
  }
  __syncthreads();
}

__device__ __forceinline__ void out_phase(int tt, int bb, int tid,
    const float* __restrict__ hsrc, const float* __restrict__ rcsrc,
    const float* __restrict__ W_out, const float* __restrict__ b_out,
    float* __restrict__ out)
{
  // 8192 outputs over 224 blocks: 37 per block; 16 lanes per output, k-interleaved.
  const int q = tid & 15, oi = tid >> 4;  // oi in 0..31
  for (int i = oi; i < 37; i += 32) {
    const int j = bb * 37 + i;
    if (j >= Bv * OUTv) break;
    const int b = j >> 8, o = j & 255;
    const float4* w4 = (const float4*)(W_out + o * (HIDv + NHv*HSv));
    const float4* h4 = (const float4*)(hsrc + b * HIDv);
    const float4* r4 = (const float4*)(rcsrc + b * (NHv*HSv));
    float a0=0.f, a1=0.f, a2=0.f, a3=0.f;
    for (int i2 = 0; i2 < 8; i2 += 4) {
      a0 += dot4(h4[(i2+0)*16 + q], w4[(i2+0)*16 + q]);
      a1 += dot4(h4[(i2+1)*16 + q], w4[(i2+1)*16 + q]);
      a2 += dot4(h4[(i2+2)*16 + q], w4[(i2+2)*16 + q]);
      a3 += dot4(h4[(i2+3)*16 + q], w4[(i2+3)*16 + q]);
    }
    for (int i2 = 8; i2 < 12; i2 += 2) {
      a0 += dot4(r4[(i2-8)*16 + q], w4[(i2+0)*16 + q]);
      a1 += dot4(r4[(i2-7)*16 + q], w4[(i2+1)*16 + q]);
    }
    float acc = (a0+a1)+(a2+a3);
    acc += __shfl_xor(acc, 1);
    acc += __shfl_xor(acc, 2);
    acc += __shfl_xor(acc, 4);
    acc += __shfl_xor(acc, 8);
    if (q == 0) out[((size_t)b * Lv + tt) * OUTv + o] = acc + b_out[o];
  }
}

__global__ __launch_bounds__(NTHR) void ntm_kernel(
    const float* __restrict__ x, const float* __restrict__ W_ih, const float* __restrict__ W_hh,
    const float* __restrict__ b_ih, const float* __restrict__ b_hh,
    const float* __restrict__ W_head, const float* __restrict__ b_head,
    const float* __restrict__ W_out, const float* __restrict__ b_out,
    float* __restrict__ out, float* __restrict__ ws)
{
  const int bk = blockIdx.x, tid = threadIdx.x;
  unsigned* bar = (unsigned*)ws;
  float* gates = ws + G_OFF;
  float* hbuf  = ws + H_OFF;   // [parity][b][512]
  float* cbuf  = ws + C_OFF;   // [parity][b][512]
  float* rcbuf = ws + R_OFF;   // [parity][b][256]
  float* hp    = ws + P_OFF;   // [b][n][129]
  float* memv  = out + (size_t)Bv * Lv * OUTv;  // mem state lives in d_out
  float* hout  = memv + Bv * MEMv * HSv;
  float* cout_ = hout + Bv * HIDv;

  __shared__ float part[NTHR];
  __shared__ __align__(16) float h_lds[HIDv];
  __shared__ __align__(16) float rk[NHv][HSv];
  __shared__ __align__(16) float wk[NHv][HSv];
  __shared__ float pr[NHv][MEMv], pw[NHv][MEMv];
  __shared__ float strl[NHv];

  // --- init: zero hbuf/cbuf/rcbuf (contiguous) and mem state ---
  for (int i = bk * NTHR + tid; i < 2*Bv*HIDv + 2*Bv*HIDv + 2*Bv*NHv*HSv; i += NBLK*NTHR)
    ws[H_OFF + i] = 0.f;
  for (int i = bk * NTHR + tid; i < Bv*MEMv*HSv; i += NBLK*NTHR)
    memv[i] = 0.f;
  gbar(bar, bk);

  for (int t = 0; t < Lv; ++t) {
    // ===== phase 1: gates(t) = [x_t, rc(t-1)] @ W_ih^T + h(t-1) @ W_hh^T + b =====
    {
      const int kh = tid >> 8, r = (tid >> 5) & 7, b = tid & 31;
      const int row = bk * 8 + r;
      const float* hprev  = hbuf  + ((t + 1) & 1) * (Bv*HIDv);
      const float* rcprev = rcbuf + ((t + 1) & 1) * (Bv*NHv*HSv);
      float a0=0.f, a1=0.f, a2=0.f, a3=0.f;
      if (kh == 0) {
        const float4* w4 = (const float4*)(W_ih + row * CTRLv);
        const float4* x4 = (const float4*)(x + ((size_t)b * Lv + t) * Ev);
        const float4* r4 = (const float4*)(rcprev + b * (NHv*HSv));
        for (int k = 0; k < 64; k += 4) {
          a0 += dot4(x4[k+0], w4[k+0]); a1 += dot4(x4[k+1], w4[k+1]);
          a2 += dot4(x4[k+2], w4[k+2]); a3 += dot4(x4[k+3], w4[k+3]);
        }
        for (int k = 0; k < 64; k += 4) {
          a0 += dot4(r4[k+0], w4[64+k+0]); a1 += dot4(r4[k+1], w4[64+k+1]);
          a2 += dot4(r4[k+2], w4[64+k+2]); a3 += dot4(r4[k+3], w4[64+k+3]);
        }
      } else {
        const float4* w4 = (const float4*)(W_hh + row * HIDv);
        const float4* h4 = (const float4*)(hprev + b * HIDv);
        for (int k = 0; k < 128; k += 4) {
          a0 += dot4(h4[k+0], w4[k+0]); a1 += dot4(h4[k+1], w4[k+1]);
          a2 += dot4(h4[k+2], w4[k+2]); a3 += dot4(h4[k+3], w4[k+3]);
        }
      }
      part[tid] = (a0 + a1) + (a2 + a3);
      __syncthreads();
      if (tid < 256) {
        const int r2 = tid >> 5, b2 = tid & 31, row2 = bk * 8 + r2;
        gates[b2 * GATESv + row2] = part[tid] + part[tid + 256] + b_ih[row2] + b_hh[row2];
      }
    }
    gbar(bar, bk);

    // ===== phase 2: LSTM pointwise (redundant per sub) + head GEMM (used rows only) =====
    {
      const int b = bk >> 3, sub = bk & 7;
      const float* gb = gates + b * GATESv;
      const int k = tid;  // 0..511, one hidden unit each
      float ig = sigm(gb[k]);
      float fg = sigm(gb[512 + k]);
      float gg = tanh_(gb[1024 + k]);
      float og = sigm(gb[1536 + k]);
      float cold = cbuf[(t & 1) * (Bv*HIDv) + b * HIDv + k];
      float cnew = fmaf(fg, cold, ig * gg);
      float hnew = og * tanh_(cnew);
      h_lds[k] = hnew;
      if (sub == 0) {
        cbuf[((t + 1) & 1) * (Bv*HIDv) + b * HIDv + k] = cnew;
        hbuf[(t & 1) * (Bv*HIDv) + b * HIDv + k] = hnew;
      }
      __syncthreads();
      // 516 used rows of W_head (read keys, write keys, strength); 8 lanes/row.
      const int q = tid & 7;
      const int li1 = (sub == 7) ? 516 : (sub * 65 + 65);
      for (int li = sub * 65 + (tid >> 3); li < li1; li += 64) {
        const int n = li / 129, d = li - n * 129;
        const int row = n * 195 + d;
        const float4* w4 = (const float4*)(W_head + row * HIDv);
        const float4* h4 = (const float4*)h_lds;
        float a0=0.f, a1=0.f, a2=0.f, a3=0.f;
        for (int i = 0; i < 16; i += 4) {
          a0 += dot4(h4[(i+0)*8 + q], w4[(i+0)*8 + q]);
          a1 += dot4(h4[(i+1)*8 + q], w4[(i+1)*8 + q]);
          a2 += dot4(h4[(i+2)*8 + q], w4[(i+2)*8 + q]);
          a3 += dot4(h4[(i+3)*8 + q], w4[(i+3)*8 + q]);
        }
        float acc = (a0+a1)+(a2+a3);
        acc += __shfl_xor(acc, 1);
        acc += __shfl_xor(acc, 2);
        acc += __shfl_xor(acc, 4);
        if (q == 0) {
          acc += b_head[row];
          if (d == 128) acc = sigm(acc);   // write strength pre-sigmoided
          hp[(b * NHv + n) * HPDv + d] = acc;
        }
      }
    }
    gbar(bar, bk);

    // ===== phase 3: attention (blocks 0..31) || out(t-1) (blocks 32..255) =====
    if (bk < Bv) {
      const int b = bk;
      for (int i = tid; i < NHv * HSv; i += NTHR) {
        const int n = i >> 6, d = i & 63;
        rk[n][d] = hp[(b*NHv + n) * HPDv + d];
        wk[n][d] = hp[(b*NHv + n) * HPDv + HSv + d];
      }
      if (tid < NHv) strl[tid] = hp[(b*NHv + tid) * HPDv + 2*HSv];
      __syncthreads();
      {
        const int n = tid >> 7, m = tid & 127;
        const float4* mr  = (const float4*)(memv + ((size_t)b * MEMv + m) * HSv);
        const float4* rk4 = (const float4*)rk[n];
        const float4* wk4 = (const float4*)wk[n];
        float sr0=0.f, sr1=0.f, sw0=0.f, sw1=0.f;
        for (int i = 0; i < 16; i += 2) {
          float4 m0 = mr[i], m1 = mr[i+1];
          sr0 += dot4(m0, rk4[i]);   sw0 += dot4(m0, wk4[i]);
          sr1 += dot4(m1, rk4[i+1]); sw1 += dot4(m1, wk4[i+1]);
        }
        pr[n][m] = (sr0 + sr1) * 0.125f;
        pw[n][m] = (sw0 + sw1) * 0.125f;
      }
      __syncthreads();
      {
        // softmax over m: 8 waves, one (tensor, head) row each
        const int w = tid >> 6, lane = tid & 63;
        float* rowp = (w < NHv) ? pr[w] : pw[w - NHv];
        float va = rowp[lane], vb = rowp[lane + 64];
        float mx = fmaxf(va, vb);
        for (int off = 32; off > 0; off >>= 1) mx = fmaxf(mx, __shfl_xor(mx, off));
        float ea = __expf(va - mx), eb = __expf(vb - mx);
        float s = ea + eb;
        for (int off = 32; off > 0; off >>= 1) s += __shfl_xor(s, off);
        float inv = 1.0f / s;
        rowp[lane] = ea * inv; rowp[lane + 64] = eb * inv;
      }
      __syncthreads();
      if (tid < NHv * HSv) {
        const int n = tid >> 6, hh = tid & 63;
        const float* mcol = memv + (size_t)b * MEMv * HSv + hh;
        float a0=0.f, a1=0.f, a2=0.f, a3=0.f;
        for (int m = 0; m < MEMv; m += 4) {
          a0 += pr[n][m+0] * mcol[(m+0) * HSv];
          a1 += pr[n][m+1] * mcol[(m+1) * HSv];
          a2 += pr[n][m+2] * mcol[(m+2) * HSv];
          a3 += pr[n][m+3] * mcol[(m+3) * HSv];
        }
        rcbuf[(t & 1) * (Bv*NHv*HSv) + (b * NHv + n) * HSv + hh] = (a0+a1)+(a2+a3);
      }
      __syncthreads();
      {
        const int hh = tid & 63, mg = tid >> 6;
        const float s0 = strl[0]*wk[0][hh], s1 = strl[1]*wk[1][hh],
                    s2 = strl[2]*wk[2][hh], s3 = strl[3]*wk[3][hh];
        for (int m = mg; m < MEMv; m += 8) {
          float add = pw[0][m]*s0 + pw[1][m]*s1 + pw[2][m]*s2 + pw[3][m]*s3;
          memv[((size_t)b * MEMv + m) * HSv + hh] += add;
        }
      }
    } else if (t > 0) {
      out_phase(t - 1, bk - 32, tid,
                hbuf  + ((t + 1) & 1) * (Bv*HIDv),
                rcbuf + ((t + 1) & 1) * (Bv*NHv*HSv),
                W_out, b_out, out);
    }
    gbar(bar, bk);
  }

  // ===== final: out(L-1) + copy h, c states to d_out =====
  if (bk >= 32) {
    out_phase(Lv - 1, bk - 32, tid,
              hbuf + (Bv*HIDv),          // h(255): parity 1
              rcbuf + (Bv*NHv*HSv),      // rc(255): parity 1
              W_out, b_out, out);
  } else {
    const int idx = bk * NTHR + tid;     // 0..16383
    hout[idx]  = hbuf[Bv*HIDv + idx];    // parity 1
    cout_[idx] = cbuf[idx];              // c(255) written to parity 0
  }
}

extern "C" void kernel_launch(void* const* d_in, const int* in_sizes, int n_in,
                              void* d_out, int out_size, void* d_ws, size_t ws_size,
                              hipStream_t stream) {
  const float* x      = (const float*)d_in[0];
  const float* W_ih   = (const float*)d_in[1];
  const float* W_hh   = (const float*)d_in[2];
  const float* b_ih   = (const float*)d_in[3];
  const float* b_hh   = (const float*)d_in[4];
  const float* W_head = (const float*)d_in[5];
  const float* b_head = (const float*)d_in[6];
  const float* W_out  = (const float*)d_in[7];
  const float* b_out  = (const float*)d_in[8];
  float* out = (float*)d_out;
  float* ws  = (float*)d_ws;

  // reset barrier state (ws is poisoned 0xAA once; must be 0 each call)
  (void)hipMemsetAsync(d_ws, 0, 4096, stream);

  void* args[] = { (void*)&x, (void*)&W_ih, (void*)&W_hh, (void*)&b_ih, (void*)&b_hh,
                   (void*)&W_head, (void*)&b_head, (void*)&W_out, (void*)&b_out,
                   (void*)&out, (void*)&ws };
  (void)hipLaunchCooperativeKernel((const void*)ntm_kernel, dim3(NBLK), dim3(NTHR),
                                   args, 0, stream);
}